// Round 2
// baseline (343.837 us; speedup 1.0000x reference)
//
#include <hip/hip_runtime.h>

#define C_     20
#define H_     64
#define W_     2048
#define HW_    (H_*W_)
#define KN     24        // 5x5 taps minus center
#define TH     4
#define TW     64
#define TR     (TH+4)    // 8
#define TC     (TW+4)    // 68
#define NCH    5         // classes per chunk
#define NCHUNK (C_/NCH)  // 4
#define CH_ELEMS  (NCH*TR*TC)   // 2720
#define CH_STRIDE 2816          // padded to 11*256 so all DMA lanes land in LDS
#define STG    11               // ceil(CH_ELEMS/256)

// async global->LDS DMA: wave-uniform LDS base + lane*4 (linear dest), per-lane global src
#define GLOAD_LDS(SRC, DST)                                                     \
    __builtin_amdgcn_global_load_lds(                                           \
        (const __attribute__((address_space(1))) void*)(SRC),                   \
        (__attribute__((address_space(3))) void*)(DST), 4, 0, 0)

__global__ __launch_bounds__(256, 4) void lp_kernel(
    const float* __restrict__ data,
    const float* __restrict__ mask,
    const float* __restrict__ bilat,
    const float* __restrict__ ang_w,
    const float* __restrict__ bi_w,
    const float* __restrict__ zbuf,   // 256 zeroed bytes in d_ws
    float* __restrict__ out)
{
    constexpr int KI[KN] = {0,0,0,0,0, 1,1,1,1,1, 2,2,2,2, 3,3,3,3,3, 4,4,4,4,4};
    constexpr int KJ[KN] = {0,1,2,3,4, 0,1,2,3,4, 0,1,3,4, 0,1,2,3,4, 0,1,2,3,4};

    __shared__ float s_data[2*CH_STRIDE];   // double-buffered chunk (22.5 KB)
    __shared__ float s_mask[TR*TC];         // 2.2 KB

    const int tid = threadIdx.x;
    const int bid = blockIdx.x;
    const int ntx = W_/TW, nty = H_/TH;
    const int tx = bid % ntx;
    const int ty = (bid/ntx) % nty;
    const int b  = bid/(ntx*nty);
    const int y0 = ty*TH, x0 = tx*TW;

    const float* dbase = data + (size_t)b*C_*HW_;

    // --- precompute per-slot halo offsets (chunk-independent) ---
    int goff[STG];
    #pragma unroll
    for (int s = 0; s < STG; ++s) {
        int idx = tid + s*256;
        int rem = idx % (TR*TC);
        int r   = rem / TC;
        int col = rem % TC;
        int gy = y0 + r - 2, gx = x0 + col - 2;
        bool ok = (idx < CH_ELEMS) && (gy >= 0) && (gy < H_) && (gx >= 0) && (gx < W_);
        goff[s] = ok ? (gy*W_ + gx) : -1;
    }

    // stage chunk CH into buffer BUF via async DMA (OOB lanes read the zero word)
    #define STAGE(CH, BUF) do {                                                        \
        _Pragma("unroll")                                                              \
        for (int s = 0; s < STG; ++s) {                                                \
            int idx = tid + s*256;                                                     \
            int c   = idx / (TR*TC);                                                   \
            const float* src = (goff[s] >= 0)                                          \
                ? (dbase + (size_t)((CH)*NCH + c)*HW_ + goff[s]) : zbuf;               \
            float* dst = s_data + (BUF)*CH_STRIDE + s*256 + (tid & ~63);               \
            GLOAD_LDS(src, dst);                                                       \
        }                                                                              \
    } while (0)

    // --- issue chunk-0 DMA, stage mask, overlap bilateral loads ---
    STAGE(0, 0);

    const float* mbase = mask + (size_t)b*HW_;
    for (int idx = tid; idx < TR*TC; idx += 256) {
        int r = idx / TC, col = idx % TC;
        int gy = y0 + r - 2, gx = x0 + col - 2;
        float v = 0.0f;
        if (gy >= 0 && gy < H_ && gx >= 0 && gx < W_) v = mbase[gy*W_ + gx];
        s_mask[idx] = v;
    }

    const int lx  = tid & 63;
    const int lyy = tid >> 6;
    const int y = y0 + lyy, x = x0 + lx;

    // bilateral values for this pixel (global, coalesced; latency hides under staging)
    float bb[KN];
    {
        const float* bibase = bilat + (size_t)b*KN*HW_ + (size_t)y*W_ + x;
        #pragma unroll
        for (int kp = 0; kp < KN; ++kp) bb[kp] = bibase[(size_t)kp*HW_];
    }

    __syncthreads();   // drains chunk-0 DMA (vmcnt) + mask ds_writes

    // mask at the 24 tap positions + center
    float mm[KN];
    #pragma unroll
    for (int k = 0; k < KN; ++k) mm[k] = s_mask[(lyy + KI[k])*TC + lx + KJ[k]];
    const float m_c = s_mask[(lyy + 2)*TC + lx + 2];

    float bi_acc[C_], biang[C_];
    #pragma unroll
    for (int c2 = 0; c2 < C_; ++c2) bi_acc[c2] = 0.0f;

    float* aout = out + ((size_t)b*C_*H_ + y)*W_ + x;
    float* bout = aout + (size_t)2*C_*HW_;   // bi block, same relative position

    #pragma unroll
    for (int ch = 0; ch < NCHUNK; ++ch) {
        if (ch + 1 < NCHUNK) STAGE(ch + 1, (ch + 1) & 1);   // prefetch next chunk

        const float* sbuf = s_data + (ch & 1)*CH_STRIDE;
        #pragma unroll
        for (int cl = 0; cl < NCH; ++cl) {
            const int cls = ch*NCH + cl;
            float a = 0.0f, ba = 0.0f;
            #pragma unroll
            for (int k = 0; k < KN; ++k) {
                const int i = KI[k], j = KJ[k];
                const float v = sbuf[cl*(TR*TC) + (lyy + i)*TC + (lx + j)];
                a  += ang_w[cls*25 + i*5 + j] * v;
                ba += bi_w [cls*25 + i*5 + j] * v;
                const int flat = k*C_ + cls;   // torch .view remap: (k,cls) -> (c',k')
                bi_acc[flat / KN] += bb[flat % KN] * (v * mm[k]);
            }
            aout[(size_t)cls*HW_] = a;
            biang[cls] = ba;
        }
        if (ch + 1 < NCHUNK) __syncthreads();  // finish ch reads + drain ch+1 DMA
    }

    #pragma unroll
    for (int c2 = 0; c2 < C_; ++c2)
        bout[(size_t)c2*HW_] = m_c * biang[c2] * bi_acc[c2];

    #undef STAGE
}

extern "C" void kernel_launch(void* const* d_in, const int* in_sizes, int n_in,
                              void* d_out, int out_size, void* d_ws, size_t ws_size,
                              hipStream_t stream) {
    const float* data  = (const float*)d_in[0];
    const float* mask  = (const float*)d_in[1];
    const float* bilat = (const float*)d_in[2];
    const float* ang_w = (const float*)d_in[3];
    const float* bi_w  = (const float*)d_in[4];
    float* out = (float*)d_out;

    hipMemsetAsync(d_ws, 0, 256, stream);   // zero word for OOB halo lanes

    const int nblocks = 2 * (H_/TH) * (W_/TW);  // 1024
    lp_kernel<<<nblocks, 256, 0, stream>>>(data, mask, bilat, ang_w, bi_w,
                                           (const float*)d_ws, out);
}

// Round 3
// 273.546 us; speedup vs baseline: 1.2570x; 1.2570x over previous
//
#include <hip/hip_runtime.h>

#define C_     20
#define H_     64
#define W_     2048
#define HW_    (H_*W_)
#define KN     24        // 5x5 taps minus center
#define TH     4
#define TW     64
#define TR     (TH+4)    // 8
#define TC     (TW+4)    // 68
#define NCH    5         // classes per chunk
#define NCHUNK 4
#define CHE    (NCH*TR*TC)   // 2720
#define STG    11            // ceil(CHE/256)
#define PADE   (STG*256)     // 2816 (dead zone 2720..2815 absorbs tail writes)

constexpr int KI[KN] = {0,0,0,0,0, 1,1,1,1,1, 2,2,2,2, 3,3,3,3,3, 4,4,4,4,4};
constexpr int KJ[KN] = {0,1,2,3,4, 0,1,2,3,4, 0,1,3,4, 0,1,2,3,4, 0,1,2,3,4};

// Prefetch chunk CH (5 class planes) into registers. CH is compile-time;
// all pf[] indexing static -> stays in VGPRs (rule #20).
template<int CH>
__device__ __forceinline__ void prefetch_chunk(const float* __restrict__ dbase,
    int tid, int y0, int x0, float (&pf)[STG])
{
#pragma unroll
    for (int s = 0; s < STG; ++s) {
        const int idx = tid + s*256;
        const int c   = idx / (TR*TC);
        const int rem = idx - c*(TR*TC);
        const int r   = rem / TC;
        const int col = rem - r*TC;
        const int gy = y0 + r - 2, gx = x0 + col - 2;
        const bool ok = (idx < CHE) & (gy >= 0) & (gy < H_) & (gx >= 0) & (gx < W_);
        pf[s] = ok ? dbase[(size_t)(CH*NCH + c)*HW_ + (gy*W_ + gx)] : 0.0f;
    }
}

// Compute 5 classes of chunk CH from LDS. All array indices compile-time.
template<int CH>
__device__ __forceinline__ void compute_chunk(const float* s_chunk,
    int lyy, int lx,
    const float* __restrict__ ang_w, const float* __restrict__ bi_w,
    const float (&bb)[KN], const float (&mm)[KN],
    float (&bi_acc)[C_], float (&biang)[C_], float* __restrict__ aout)
{
#pragma unroll
    for (int cl = 0; cl < NCH; ++cl) {
        const int cls = CH*NCH + cl;
        float a = 0.0f, ba = 0.0f;
        const float* srow = s_chunk + cl*(TR*TC) + lyy*TC + lx;
#pragma unroll
        for (int k = 0; k < KN; ++k) {
            const int i = KI[k], j = KJ[k];
            const float v = srow[i*TC + j];           // adjacent j's merge to ds_read2_b32
            a  += ang_w[cls*25 + i*5 + j] * v;        // wave-uniform -> s_load
            ba += bi_w [cls*25 + i*5 + j] * v;
            const int flat = k*C_ + cls;              // torch .view remap (k,cls)->(c',k')
            bi_acc[flat / KN] += bb[flat % KN] * (v * mm[k]);
        }
        aout[(size_t)cls*HW_] = a;
        biang[cls] = ba;
    }
}

__global__ __launch_bounds__(256, 4) void lp_kernel(
    const float* __restrict__ data,
    const float* __restrict__ mask,
    const float* __restrict__ bilat,
    const float* __restrict__ ang_w,
    const float* __restrict__ bi_w,
    float* __restrict__ out)
{
    __shared__ float s_chunk[PADE];    // 11.26 KB
    __shared__ float s_mask[TR*TC];    // 2.18 KB

    const int tid = threadIdx.x;
    int bid = blockIdx.x;
    bid = (bid & 7)*128 + (bid >> 3);  // XCD swizzle (1024 % 8 == 0, bijective)

    const int tx = bid & 31;           // W_/TW = 32
    const int ty = (bid >> 5) & 15;    // H_/TH = 16
    const int b  = bid >> 9;
    const int y0 = ty*TH, x0 = tx*TW;
    const float* dbase = data + (size_t)b*C_*HW_;

    const int lx  = tid & 63;
    const int lyy = tid >> 6;
    const int y = y0 + lyy, x = x0 + lx;

    // bilateral per-pixel values — issue early, latency hides under staging
    float bb[KN];
    {
        const float* bibase = bilat + (size_t)b*KN*HW_ + (size_t)y*W_ + x;
#pragma unroll
        for (int kp = 0; kp < KN; ++kp) bb[kp] = bibase[(size_t)kp*HW_];
    }

    // stage mask tile (written once, read all kernel)
    {
        const float* mbase = mask + (size_t)b*HW_;
#pragma unroll
        for (int s = 0; s < 3; ++s) {
            const int idx = tid + s*256;
            if (idx < TR*TC) {
                const int r = idx / TC, col = idx - r*TC;
                const int gy = y0 + r - 2, gx = x0 + col - 2;
                const bool ok = (gy >= 0) & (gy < H_) & (gx >= 0) & (gx < W_);
                s_mask[idx] = ok ? mbase[gy*W_ + gx] : 0.0f;
            }
        }
    }

    float pf[STG];
    prefetch_chunk<0>(dbase, tid, y0, x0, pf);
#pragma unroll
    for (int s = 0; s < STG; ++s) s_chunk[tid + s*256] = pf[s];
    __syncthreads();   // covers mask writes + chunk0 writes

    // mask taps for this pixel
    float mm[KN];
#pragma unroll
    for (int k = 0; k < KN; ++k) mm[k] = s_mask[(lyy + KI[k])*TC + (lx + KJ[k])];
    const float m_c = s_mask[(lyy + 2)*TC + (lx + 2)];

    float bi_acc[C_], biang[C_];
#pragma unroll
    for (int c2 = 0; c2 < C_; ++c2) bi_acc[c2] = 0.0f;

    float* aout = out + ((size_t)b*C_*H_ + y)*W_ + x;
    float* bout = aout + (size_t)2*C_*HW_;

    // --- explicit phases: prefetch(ch+1) -> compute(ch) -> sync -> write -> sync ---
    prefetch_chunk<1>(dbase, tid, y0, x0, pf);
    compute_chunk<0>(s_chunk, lyy, lx, ang_w, bi_w, bb, mm, bi_acc, biang, aout);
    __syncthreads();
#pragma unroll
    for (int s = 0; s < STG; ++s) s_chunk[tid + s*256] = pf[s];
    __syncthreads();

    prefetch_chunk<2>(dbase, tid, y0, x0, pf);
    compute_chunk<1>(s_chunk, lyy, lx, ang_w, bi_w, bb, mm, bi_acc, biang, aout);
    __syncthreads();
#pragma unroll
    for (int s = 0; s < STG; ++s) s_chunk[tid + s*256] = pf[s];
    __syncthreads();

    prefetch_chunk<3>(dbase, tid, y0, x0, pf);
    compute_chunk<2>(s_chunk, lyy, lx, ang_w, bi_w, bb, mm, bi_acc, biang, aout);
    __syncthreads();
#pragma unroll
    for (int s = 0; s < STG; ++s) s_chunk[tid + s*256] = pf[s];
    __syncthreads();

    compute_chunk<3>(s_chunk, lyy, lx, ang_w, bi_w, bb, mm, bi_acc, biang, aout);

#pragma unroll
    for (int c2 = 0; c2 < C_; ++c2)
        bout[(size_t)c2*HW_] = m_c * biang[c2] * bi_acc[c2];
}

extern "C" void kernel_launch(void* const* d_in, const int* in_sizes, int n_in,
                              void* d_out, int out_size, void* d_ws, size_t ws_size,
                              hipStream_t stream) {
    const float* data  = (const float*)d_in[0];
    const float* mask  = (const float*)d_in[1];
    const float* bilat = (const float*)d_in[2];
    const float* ang_w = (const float*)d_in[3];
    const float* bi_w  = (const float*)d_in[4];
    float* out = (float*)d_out;

    const int nblocks = 2 * (H_/TH) * (W_/TW);  // 1024
    lp_kernel<<<nblocks, 256, 0, stream>>>(data, mask, bilat, ang_w, bi_w, out);
}

// Round 4
// 33.555 us; speedup vs baseline: 10.2470x; 8.1522x over previous
//
#include <hip/hip_runtime.h>

#define C_     20
#define H_     64
#define W_     2048
#define HW_    (H_*W_)
#define KN     24          // 5x5 taps minus center
#define TH     8
#define TW     64
#define TR     (TH+4)      // 12
#define TC     (TW+4)      // 68
#define PLANE  (TR*TC)     // 816 floats per class plane
#define DELEMS (C_*PLANE)  // 16320
#define DPAD   16384       // 32*512, tail 64 slots are dead pad
#define NTHR   512
#define DSTG   (DPAD/NTHR) // 32
#define MPAD   1024        // mask 816 -> pad

// async global->LDS: wave-uniform LDS base, HW adds lane*4; per-lane global src
#define GLOAD_LDS(SRC, DST)                                                     \
    __builtin_amdgcn_global_load_lds(                                           \
        (const __attribute__((address_space(1))) void*)(SRC),                   \
        (__attribute__((address_space(3))) void*)(DST), 4, 0, 0)

constexpr int KI[KN] = {0,0,0,0,0, 1,1,1,1,1, 2,2,2,2, 3,3,3,3,3, 4,4,4,4,4};
constexpr int KJ[KN] = {0,1,2,3,4, 0,1,2,3,4, 0,1,3,4, 0,1,2,3,4, 0,1,2,3,4};

__global__ __launch_bounds__(NTHR, 4) void lp_kernel(
    const float* __restrict__ data,
    const float* __restrict__ mask,
    const float* __restrict__ bilat,
    const float* __restrict__ ang_w,
    const float* __restrict__ bi_w,
    const float* __restrict__ zbuf,
    float* __restrict__ out)
{
    __shared__ float s_data[DPAD];   // 64 KB: 20 class planes of 12x68
    __shared__ float s_mask[MPAD];   // 4 KB

    const int tid = threadIdx.x;
    int bid = blockIdx.x;
    bid = (bid & 7)*64 + (bid >> 3);     // XCD swizzle, 512 % 8 == 0 -> bijective

    const int tx = bid & 31;             // W/TW = 32
    const int ty = (bid >> 5) & 7;       // H/TH = 8
    const int b  = bid >> 8;
    const int y0 = ty*TH, x0 = tx*TW;

    const float* dbase = data + (size_t)b*C_*HW_;
    const float* mbase = mask + (size_t)b*HW_;
    const int wbase = tid & ~63;         // wave-uniform lane-0 slot

    // ---- async DMA: data tile (all 20 classes, halo 2, OOB lanes pull zero word) ----
#pragma unroll
    for (int s = 0; s < DSTG; ++s) {
        const int idx = tid + s*NTHR;
        const int cls = idx / PLANE;
        const int rem = idx - cls*PLANE;
        const int r   = rem / TC;
        const int col = rem - r*TC;
        const int gy = y0 + r - 2, gx = x0 + col - 2;
        const bool ok = (idx < DELEMS) & (gy >= 0) & (gy < H_) & (gx >= 0) & (gx < W_);
        const float* src = ok ? (dbase + (size_t)cls*HW_ + (gy*W_ + gx)) : zbuf;
        GLOAD_LDS(src, s_data + s*NTHR + wbase);
    }
    // ---- async DMA: mask tile ----
#pragma unroll
    for (int s = 0; s < MPAD/NTHR; ++s) {
        const int idx = tid + s*NTHR;
        const int r   = idx / TC;
        const int col = idx - r*TC;
        const int gy = y0 + r - 2, gx = x0 + col - 2;
        const bool ok = (idx < PLANE) & (gy >= 0) & (gy < H_) & (gx >= 0) & (gx < W_);
        const float* src = ok ? (mbase + (gy*W_ + gx)) : zbuf;
        GLOAD_LDS(src, s_mask + s*NTHR + wbase);
    }

    const int lx  = tid & 63;
    const int lyy = tid >> 6;            // 8 waves = 8 tile rows
    const int y = y0 + lyy, x = x0 + lx;

    // bilateral per-pixel loads — overlap the DMA
    float bb[KN];
    {
        const float* bibase = bilat + (size_t)b*KN*HW_ + (size_t)y*W_ + x;
#pragma unroll
        for (int kp = 0; kp < KN; ++kp) bb[kp] = bibase[(size_t)kp*HW_];
    }

    __syncthreads();   // drains DMA vmcnt + makes LDS visible

    float mm[KN];
#pragma unroll
    for (int k = 0; k < KN; ++k) mm[k] = s_mask[(lyy + KI[k])*TC + (lx + KJ[k])];
    const float m_c = s_mask[(lyy + 2)*TC + (lx + 2)];

    float bi_acc[C_], biang[C_];
#pragma unroll
    for (int c2 = 0; c2 < C_; ++c2) bi_acc[c2] = 0.0f;

    float* aout = out + ((size_t)b*C_*H_ + y)*W_ + x;
    float* bout = aout + (size_t)2*C_*HW_;

#pragma unroll
    for (int cls = 0; cls < C_; ++cls) {
        float a = 0.0f, ba = 0.0f;
        const float* srow = s_data + cls*PLANE + lyy*TC + lx;
#pragma unroll
        for (int k = 0; k < KN; ++k) {
            const int i = KI[k], j = KJ[k];
            const float v = srow[i*TC + j];          // base + imm offset; pairs -> ds_read2
            a  += ang_w[cls*25 + i*5 + j] * v;       // wave-uniform -> s_load
            ba += bi_w [cls*25 + i*5 + j] * v;
            const int flat = k*C_ + cls;             // torch .view remap (k,cls)->(c',k')
            bi_acc[flat / KN] += bb[flat % KN] * (v * mm[k]);
        }
        aout[(size_t)cls*HW_] = a;
        biang[cls] = ba;
    }

#pragma unroll
    for (int c2 = 0; c2 < C_; ++c2)
        bout[(size_t)c2*HW_] = m_c * biang[c2] * bi_acc[c2];
}

extern "C" void kernel_launch(void* const* d_in, const int* in_sizes, int n_in,
                              void* d_out, int out_size, void* d_ws, size_t ws_size,
                              hipStream_t stream) {
    const float* data  = (const float*)d_in[0];
    const float* mask  = (const float*)d_in[1];
    const float* bilat = (const float*)d_in[2];
    const float* ang_w = (const float*)d_in[3];
    const float* bi_w  = (const float*)d_in[4];
    float* out = (float*)d_out;

    hipMemsetAsync(d_ws, 0, 256, stream);   // zero word for OOB halo lanes

    const int nblocks = 2 * (H_/TH) * (W_/TW);  // 512
    lp_kernel<<<nblocks, NTHR, 0, stream>>>(data, mask, bilat, ang_w, bi_w,
                                            (const float*)d_ws, out);
}